// Round 1
// baseline (1637.881 us; speedup 1.0000x reference)
//
#include <hip/hip_runtime.h>
#include <math.h>

#define HH 1536
#define EE 512
#define TT 48
#define SS 32

// Workspace layout (floats): h1a[H], h1b[H], h2a[H], h2b[H], c1[H], c2[H], then int xid
// Harness poisons ws each launch -> init kernel zeroes state and sets xid.

__device__ __forceinline__ float sigf(float x) { return 1.0f / (1.0f + expf(-x)); }

__global__ __launch_bounds__(256) void init_kernel(float* ws, const int* __restrict__ input_id) {
    for (int i = threadIdx.x; i < 6 * HH; i += blockDim.x) ws[i] = 0.0f;
    if (threadIdx.x == 0) {
        *(int*)(ws + 6 * HH) = *input_id;
    }
}

// cell1: x = emb[*xid] (length E=512), recurrent input h_prev (length H)
__global__ __launch_bounds__(256) void cell1_kernel(
    const float* __restrict__ emb, const int* __restrict__ xid,
    const float* __restrict__ Wih, const float* __restrict__ Whh,
    const float* __restrict__ bih, const float* __restrict__ bhh,
    const float* __restrict__ h_prev, float* __restrict__ h_new,
    float* __restrict__ c)
{
    const int wave = threadIdx.x >> 6;
    const int lane = threadIdx.x & 63;
    const int j = blockIdx.x * 4 + wave;   // h index this wave owns

    const float* xv = emb + (size_t)(*xid) * EE;
    const float4* xv4 = (const float4*)xv;
    const float4* hp4 = (const float4*)h_prev;

    float g[4];
#pragma unroll
    for (int gg = 0; gg < 4; ++gg) {
        const int r = j + gg * HH;  // gate order: i, f, g, o
        const float4* wi4 = (const float4*)(Wih + (size_t)r * EE);
        const float4* wh4 = (const float4*)(Whh + (size_t)r * HH);
        float acc = 0.0f;
#pragma unroll
        for (int i = 0; i < EE / 256; ++i) {   // 2 iters
            float4 a = wi4[lane + 64 * i];
            float4 b = xv4[lane + 64 * i];
            acc += a.x * b.x + a.y * b.y + a.z * b.z + a.w * b.w;
        }
#pragma unroll
        for (int i = 0; i < HH / 256; ++i) {   // 6 iters
            float4 a = wh4[lane + 64 * i];
            float4 b = hp4[lane + 64 * i];
            acc += a.x * b.x + a.y * b.y + a.z * b.z + a.w * b.w;
        }
#pragma unroll
        for (int off = 32; off; off >>= 1) acc += __shfl_down(acc, off);
        g[gg] = acc;
    }

    if (lane == 0) {
        float gi = g[0] + bih[j] + bhh[j];
        float gf = g[1] + bih[j + HH] + bhh[j + HH];
        float gc = g[2] + bih[j + 2 * HH] + bhh[j + 2 * HH];
        float go = g[3] + bih[j + 3 * HH] + bhh[j + 3 * HH];
        float cn = sigf(gf) * c[j] + sigf(gi) * tanhf(gc);
        h_new[j] = sigf(go) * tanhf(cn);
        c[j] = cn;
    }
}

// cell2: input vector xv (length H), recurrent h_prev (length H)
__global__ __launch_bounds__(256) void cell2_kernel(
    const float* __restrict__ xv,
    const float* __restrict__ Wih, const float* __restrict__ Whh,
    const float* __restrict__ bih, const float* __restrict__ bhh,
    const float* __restrict__ h_prev, float* __restrict__ h_new,
    float* __restrict__ c)
{
    const int wave = threadIdx.x >> 6;
    const int lane = threadIdx.x & 63;
    const int j = blockIdx.x * 4 + wave;

    const float4* xv4 = (const float4*)xv;
    const float4* hp4 = (const float4*)h_prev;

    float g[4];
#pragma unroll
    for (int gg = 0; gg < 4; ++gg) {
        const int r = j + gg * HH;
        const float4* wi4 = (const float4*)(Wih + (size_t)r * HH);
        const float4* wh4 = (const float4*)(Whh + (size_t)r * HH);
        float acc = 0.0f;
#pragma unroll
        for (int i = 0; i < HH / 256; ++i) {   // 6 iters
            float4 a = wi4[lane + 64 * i];
            float4 b = xv4[lane + 64 * i];
            acc += a.x * b.x + a.y * b.y + a.z * b.z + a.w * b.w;
        }
#pragma unroll
        for (int i = 0; i < HH / 256; ++i) {   // 6 iters
            float4 a = wh4[lane + 64 * i];
            float4 b = hp4[lane + 64 * i];
            acc += a.x * b.x + a.y * b.y + a.z * b.z + a.w * b.w;
        }
#pragma unroll
        for (int off = 32; off; off >>= 1) acc += __shfl_down(acc, off);
        g[gg] = acc;
    }

    if (lane == 0) {
        float gi = g[0] + bih[j] + bhh[j];
        float gf = g[1] + bih[j + HH] + bhh[j + HH];
        float gc = g[2] + bih[j + 2 * HH] + bhh[j + 2 * HH];
        float go = g[3] + bih[j + 3 * HH] + bhh[j + 3 * HH];
        float cn = sigf(gf) * c[j] + sigf(gi) * tanhf(gc);
        h_new[j] = sigf(go) * tanhf(cn);
        c[j] = cn;
    }
}

// head: logits = Wo @ h2 + bo ; log_softmax -> out[t]; argmax -> next xid
__global__ __launch_bounds__(1024) void head_kernel(
    const float* __restrict__ h2, const float* __restrict__ Wo,
    const float* __restrict__ bo, float* __restrict__ outp,
    int* __restrict__ xid, int t)
{
    __shared__ float z[SS];
    __shared__ float m_s, l_s;
    const int wave = threadIdx.x >> 6;
    const int lane = threadIdx.x & 63;
    const float4* h4 = (const float4*)h2;

    for (int s = wave; s < SS; s += 16) {
        const float4* w4 = (const float4*)(Wo + (size_t)s * HH);
        float acc = 0.0f;
#pragma unroll
        for (int i = 0; i < HH / 256; ++i) {
            float4 a = w4[lane + 64 * i];
            float4 b = h4[lane + 64 * i];
            acc += a.x * b.x + a.y * b.y + a.z * b.z + a.w * b.w;
        }
#pragma unroll
        for (int off = 32; off; off >>= 1) acc += __shfl_down(acc, off);
        if (lane == 0) z[s] = acc + bo[s];
    }
    __syncthreads();
    if (threadIdx.x == 0) {
        float m = z[0];
        int am = 0;
        for (int s = 1; s < SS; ++s) {
            if (z[s] > m) { m = z[s]; am = s; }
        }
        float l = 0.0f;
        for (int s = 0; s < SS; ++s) l += expf(z[s] - m);
        m_s = m;
        l_s = logf(l);
        *xid = (t & 3) * SS + am;   // (t % SIZE) * S + pred
    }
    __syncthreads();
    if (threadIdx.x < SS) outp[threadIdx.x] = z[threadIdx.x] - m_s - l_s;
}

extern "C" void kernel_launch(void* const* d_in, const int* in_sizes, int n_in,
                              void* d_out, int out_size, void* d_ws, size_t ws_size,
                              hipStream_t stream) {
    const int*   input_id = (const int*)d_in[0];
    const float* emb  = (const float*)d_in[1];
    const float* Wih1 = (const float*)d_in[2];
    const float* Whh1 = (const float*)d_in[3];
    const float* bih1 = (const float*)d_in[4];
    const float* bhh1 = (const float*)d_in[5];
    const float* Wih2 = (const float*)d_in[6];
    const float* Whh2 = (const float*)d_in[7];
    const float* bih2 = (const float*)d_in[8];
    const float* bhh2 = (const float*)d_in[9];
    const float* Wout = (const float*)d_in[10];
    const float* bout = (const float*)d_in[11];
    float* out = (float*)d_out;

    float* ws  = (float*)d_ws;
    float* h1a = ws;
    float* h1b = ws + HH;
    float* h2a = ws + 2 * HH;
    float* h2b = ws + 3 * HH;
    float* c1  = ws + 4 * HH;
    float* c2  = ws + 5 * HH;
    int*   xid = (int*)(ws + 6 * HH);

    init_kernel<<<1, 256, 0, stream>>>(ws, input_id);

    for (int t = 0; t < TT; ++t) {
        float* h1p = (t & 1) ? h1b : h1a;
        float* h1c = (t & 1) ? h1a : h1b;
        float* h2p = (t & 1) ? h2b : h2a;
        float* h2c = (t & 1) ? h2a : h2b;

        cell1_kernel<<<HH / 4, 256, 0, stream>>>(emb, xid, Wih1, Whh1, bih1, bhh1,
                                                 h1p, h1c, c1);
        cell2_kernel<<<HH / 4, 256, 0, stream>>>(h1c, Wih2, Whh2, bih2, bhh2,
                                                 h2p, h2c, c2);
        head_kernel<<<1, 1024, 0, stream>>>(h2c, Wout + (size_t)t * SS * HH,
                                            bout + (size_t)t * SS,
                                            out + (size_t)t * SS, xid, t);
    }
}